// Round 4
// baseline (342.798 us; speedup 1.0000x reference)
//
#include <hip/hip_runtime.h>
#include <cstdint>
#include <cstring>

// ---------------------------------------------------------------------------
// GQA forward, all-bf16 MFMA pipeline.  B=2, L=2048, D=2048, HQ=32, HKV=8, HD=64.
// Round 8: attention pipeline deepened + XCD-aware placement.
//   - K/V LDS ring: 3 slots (96 KB), prefetch TWO tiles ahead.
//   - Counted s_waitcnt vmcnt(4) + raw s_barrier per tile (never vmcnt(0) in
//     the main loop) -> the __syncthreads drain that pinned prefetch depth at
//     1 and emptied the VMEM queue every tile is gone (T4).
//   - Bijective XCD swizzle: the 4 qt-blocks sharing one (hq,b) K/V stream
//     map to the same XCD -> KV fetched from HBM once, L2-served after.
//   - Inner-loop math identical to verified Round 7 (permswap, setprio,
//     source-side XOR chunk swizzle, no online max).
// ---------------------------------------------------------------------------

#define L_SEQ 2048
#define D_MODEL 2048
#define M_ROWS 4096              // B*L
#define KV_COLS 512              // HKV*HD
#define ATTN_SCALE 0.18033688011112042f   // log2(e)/sqrt(64), folded into K

typedef __bf16 bf16x8 __attribute__((ext_vector_type(8)));
typedef float f32x4 __attribute__((ext_vector_type(4)));
typedef float f32x16 __attribute__((ext_vector_type(16)));

__device__ __forceinline__ f32x4 zero4() {
    f32x4 v; v[0] = 0.f; v[1] = 0.f; v[2] = 0.f; v[3] = 0.f; return v;
}

__device__ __forceinline__ unsigned short f2bf(float x) {
    unsigned u = __builtin_bit_cast(unsigned, x);
    u = (u + 0x7FFFu + ((u >> 16) & 1u)) >> 16;   // RNE
    return (unsigned short)u;
}

__device__ __forceinline__ unsigned pk_bf16(float a, float b) {
#if __has_builtin(__builtin_amdgcn_cvt_pk_bf16_f32)
    typedef __bf16 bf16x2 __attribute__((ext_vector_type(2)));
    bf16x2 r = __builtin_amdgcn_cvt_pk_bf16_f32(a, b);
    return __builtin_bit_cast(unsigned, r);
#else
    return (unsigned)f2bf(a) | ((unsigned)f2bf(b) << 16);
#endif
}

__device__ __forceinline__ f32x4 mfma16(uint4 a, uint4 b, f32x4 c) {
    return __builtin_amdgcn_mfma_f32_16x16x32_bf16(
        __builtin_bit_cast(bf16x8, a), __builtin_bit_cast(bf16x8, b), c, 0, 0, 0);
}
__device__ __forceinline__ f32x16 mfma32(uint4 a, uint4 b, f32x16 c) {
    return __builtin_amdgcn_mfma_f32_32x32x16_bf16(
        __builtin_bit_cast(bf16x8, a), __builtin_bit_cast(bf16x8, b), c, 0, 0, 0);
}

__device__ __forceinline__ void gl_lds16(const unsigned short* g, unsigned short* l) {
    __builtin_amdgcn_global_load_lds(
        (const __attribute__((address_space(1))) unsigned int*)g,
        (__attribute__((address_space(3))) unsigned int*)l, 16, 0, 0);
}

#if __has_builtin(__builtin_amdgcn_exp2f)
#define EXP2F(x) __builtin_amdgcn_exp2f(x)
#else
#define EXP2F(x) exp2f(x)
#endif

// a.hi <-> b.lo lane exchange: after this, for lanes<32 a=own, b=partner(+32);
// for lanes>=32 a=partner(-32), b=own.
__device__ __forceinline__ void permswap32(unsigned& a, unsigned& b) {
    asm("v_permlane32_swap_b32 %0, %1" : "+v"(a), "+v"(b));
}

// counted-vmcnt barrier: oldest loads guaranteed landed, newest stay in flight
__device__ __forceinline__ void bar_vm(int keep /* must be literal-selected */) {
    // callers use the two wrappers below so the immediate is compile-time
}
__device__ __forceinline__ void bar_vm4() {
    asm volatile("s_waitcnt vmcnt(4)" ::: "memory");
    __builtin_amdgcn_s_barrier();
    asm volatile("" ::: "memory");
}
__device__ __forceinline__ void bar_vm0() {
    asm volatile("s_waitcnt vmcnt(0)" ::: "memory");
    __builtin_amdgcn_s_barrier();
    asm volatile("" ::: "memory");
}

// ---------------------------------------------------------------------------
// prep kernels
// ---------------------------------------------------------------------------

__global__ __launch_bounds__(256) void cast_x_kernel(const float* __restrict__ in,
                                                     unsigned short* __restrict__ out,
                                                     int n4) {
    int i = blockIdx.x * 256 + threadIdx.x;
    if (i >= n4) return;
    float4 v = ((const float4*)in)[i];
    uint2 o;
    o.x = pk_bf16(v.x, v.y);
    o.y = pk_bf16(v.z, v.w);
    ((uint2*)out)[i] = o;
}

__global__ __launch_bounds__(256) void transpose_cast_kernel(const float* __restrict__ in,
                                                             unsigned short* __restrict__ out,
                                                             int N, int row_off) {
    __shared__ float tile[32][33];
    const int n0 = blockIdx.x * 32, k0 = blockIdx.y * 32;
    const int tc = threadIdx.x & 31, tr = threadIdx.x >> 5;
#pragma unroll
    for (int i = 0; i < 4; ++i)
        tile[tr + i * 8][tc] = in[(size_t)(k0 + tr + i * 8) * N + n0 + tc];
    __syncthreads();
#pragma unroll
    for (int i = 0; i < 4; ++i)
        out[(size_t)(row_off + n0 + tr + i * 8) * 2048 + k0 + tc] = f2bf(tile[tc][tr + i * 8]);
}

// Vb [B*L, 512] bf16  ->  Vt [(b*8+kvh)*64+d, 2048] bf16  (per-b transpose)
__global__ __launch_bounds__(256) void transpose_v_kernel(const unsigned short* __restrict__ Vb,
                                                          unsigned short* __restrict__ Vt) {
    __shared__ unsigned short tile[32][33];
    const int c0 = blockIdx.x * 32, l0 = blockIdx.y * 32, b = blockIdx.z;
    const int tc = threadIdx.x & 31, tr = threadIdx.x >> 5;
#pragma unroll
    for (int i = 0; i < 4; ++i)
        tile[tr + i * 8][tc] = Vb[(size_t)(b * 2048 + l0 + tr + i * 8) * KV_COLS + c0 + tc];
    __syncthreads();
#pragma unroll
    for (int i = 0; i < 4; ++i)
        Vt[(size_t)(b * 512 + c0 + tr + i * 8) * 2048 + l0 + tc] = tile[tc][tr + i * 8];
}

// ---------------------------------------------------------------------------
// GEMM core (m97 structure): C[128x128] = A[M,2048] * Bt[N,2048]^T
// ---------------------------------------------------------------------------

__device__ __forceinline__ void gemm_core_2048(const unsigned short* __restrict__ A,
                                               const unsigned short* __restrict__ Bt,
                                               int m_block, int n_block,
                                               unsigned short* smA, unsigned short* smB,
                                               f32x4 acc[4][4]) {
    const int tid = threadIdx.x;
    const int w = tid >> 6, lane = tid & 63;
    const int wm = w >> 1, wn = w & 1;
    const int lr = lane & 15, lg = lane >> 4;

#pragma unroll
    for (int i = 0; i < 4; ++i)
#pragma unroll
        for (int j = 0; j < 4; ++j) acc[i][j] = zero4();

    const int rowA = m_block * 128 + w * 32 + (lane >> 2);
    const int rowB = n_block * 128 + w * 32 + (lane >> 2);
    const int kcol = (lane & 3) * 8;
    const unsigned short* gA0 = A + (size_t)rowA * 2048 + kcol;
    const unsigned short* gA1 = gA0 + (size_t)16 * 2048;
    const unsigned short* gB0 = Bt + (size_t)rowB * 2048 + kcol;
    const unsigned short* gB1 = gB0 + (size_t)16 * 2048;
    unsigned short* lA0 = smA + (w * 32) * 32;
    unsigned short* lA1 = smA + (w * 32 + 16) * 32;
    unsigned short* lB0 = smB + (w * 32) * 32;
    unsigned short* lB1 = smB + (w * 32 + 16) * 32;

    for (int kt = 0; kt < 64; ++kt) {
        gl_lds16(gA0 + kt * 32, lA0);
        gl_lds16(gA1 + kt * 32, lA1);
        gl_lds16(gB0 + kt * 32, lB0);
        gl_lds16(gB1 + kt * 32, lB1);
        __syncthreads();
        uint4 af[4], bfg[4];
#pragma unroll
        for (int i = 0; i < 4; ++i)
            af[i] = *(const uint4*)(smA + (wm * 64 + i * 16 + lr) * 32 + lg * 8);
#pragma unroll
        for (int j = 0; j < 4; ++j)
            bfg[j] = *(const uint4*)(smB + (wn * 64 + j * 16 + lr) * 32 + lg * 8);
#pragma unroll
        for (int i = 0; i < 4; ++i)
#pragma unroll
            for (int j = 0; j < 4; ++j)
                acc[i][j] = mfma16(af[i], bfg[j], acc[i][j]);
        __syncthreads();
    }
}

// GEMM1: X*[Wq|Wk|Wv] + bias -> Q [4096,2048], K [4096,512] (pre-scaled), V [4096,512]
__global__ __launch_bounds__(256) void gemm_qkv_kernel(
    const unsigned short* __restrict__ Xb, const unsigned short* __restrict__ Wt,
    const float* __restrict__ bq, const float* __restrict__ bk, const float* __restrict__ bv,
    unsigned short* __restrict__ Qb, unsigned short* __restrict__ Kb,
    unsigned short* __restrict__ Vb) {
    __shared__ __align__(16) unsigned short smA[128 * 32];
    __shared__ __align__(16) unsigned short smB[128 * 32];
    f32x4 acc[4][4];
    gemm_core_2048(Xb, Wt, blockIdx.x, blockIdx.y, smA, smB, acc);

    const int tid = threadIdx.x;
    const int w = tid >> 6, lane = tid & 63;
    const int wm = w >> 1, wn = w & 1;
    const int lr = lane & 15, lg = lane >> 4;
    const int nbase = blockIdx.y * 128;

    unsigned short* outp; int ldo, noff; const float* bias; float scale;
    if (nbase < 2048)      { outp = Qb; ldo = 2048; noff = 0;    bias = bq; scale = 1.f; }
    else if (nbase < 2560) { outp = Kb; ldo = 512;  noff = 2048; bias = bk; scale = ATTN_SCALE; }
    else                   { outp = Vb; ldo = 512;  noff = 2560; bias = bv; scale = 1.f; }

#pragma unroll
    for (int i = 0; i < 4; ++i) {
        const int mrow = blockIdx.x * 128 + wm * 64 + i * 16 + lg * 4;
#pragma unroll
        for (int j = 0; j < 4; ++j) {
            const int nloc = nbase + wn * 64 + j * 16 + lr - noff;
            const float bb = bias[nloc];
#pragma unroll
            for (int r = 0; r < 4; ++r)
                outp[(size_t)(mrow + r) * ldo + nloc] = f2bf((acc[i][j][r] + bb) * scale);
        }
    }
}

// GEMM2: ctx * Wo^T + bo -> fp32 out [4096,2048]
__global__ __launch_bounds__(256) void gemm_out_kernel(
    const unsigned short* __restrict__ Cb, const unsigned short* __restrict__ Wot,
    const float* __restrict__ bo, float* __restrict__ out) {
    __shared__ __align__(16) unsigned short smA[128 * 32];
    __shared__ __align__(16) unsigned short smB[128 * 32];
    f32x4 acc[4][4];
    gemm_core_2048(Cb, Wot, blockIdx.x, blockIdx.y, smA, smB, acc);

    const int tid = threadIdx.x;
    const int w = tid >> 6, lane = tid & 63;
    const int wm = w >> 1, wn = w & 1;
    const int lr = lane & 15, lg = lane >> 4;

#pragma unroll
    for (int i = 0; i < 4; ++i) {
        const int mrow = blockIdx.x * 128 + wm * 64 + i * 16 + lg * 4;
#pragma unroll
        for (int j = 0; j < 4; ++j) {
            const int ncol = blockIdx.y * 128 + wn * 64 + j * 16 + lr;
            const float bb = bo[ncol];
#pragma unroll
            for (int r = 0; r < 4; ++r)
                out[(size_t)(mrow + r) * 2048 + ncol] = acc[i][j][r] + bb;
        }
    }
}

// ---------------------------------------------------------------------------
// Attention v8: block = 512 thr = 8 waves; each wave owns 64 q (2 q-frags,
// u=0/1) of one q-head; block covers 512 q.  Grid 256 linear blocks (1/CU);
// XCD swizzle groups the 4 qt-blocks of each (hq,b) onto one XCD.
// K tile [128 k][64 d] + V^T tile [64 d][128 k] in a 3-slot ring (96 KB LDS);
// tiles t+1 and t+2 in flight; per-tile barrier is s_waitcnt vmcnt(4) +
// s_barrier (no vmcnt(0) drain).  P assembly via v_permlane32_swap_b32;
// s_setprio(1) around MFMA clusters.  No online max.
// ---------------------------------------------------------------------------

__global__ __launch_bounds__(512, 2) void attn_kernel(const unsigned short* __restrict__ Qb,
                                                      const unsigned short* __restrict__ Kb,
                                                      const unsigned short* __restrict__ Vtg,
                                                      unsigned short* __restrict__ ctx) {
    __shared__ __align__(16) unsigned short smem[49152];   // 96 KB: 3 x (K 16KB + V 16KB)

    // XCD swizzle: assume xcd = blockIdx % 8 (perf-only assumption).
    // 64 (hq,b) groups x 4 qt members; 8 groups per XCD.
    const int p = blockIdx.x;
    const int x = p & 7, j = p >> 3;          // j in [0,32)
    const int group = x * 8 + (j >> 2);       // [0,64)
    const int qt = j & 3;
    const int hq = group & 31, b = group >> 5;
    const int kvh = hq >> 2;

    const int tid = threadIdx.x;
    const int w = tid >> 6, lane = tid & 63;
    const int l31 = lane & 31, h = lane >> 5;

    // Q B-frags for two 32-q blocks (u=0,1): B[n=q=l31][k=d], k-elem = h*8+j
    const int qbase = qt * 512 + w * 64;
    uint4 qf[2][4];
#pragma unroll
    for (int u = 0; u < 2; ++u) {
        const unsigned short* qp =
            Qb + (size_t)(b * L_SEQ + qbase + u * 32 + l31) * 2048 + hq * 64;
#pragma unroll
        for (int dh = 0; dh < 4; ++dh)
            qf[u][dh] = *(const uint4*)(qp + dh * 16 + h * 8);
    }

    f32x16 o00, o01, o10, o11;   // o[u][d-half]
#pragma unroll
    for (int r = 0; r < 16; ++r) { o00[r] = 0.f; o01[r] = 0.f; o10[r] = 0.f; o11[r] = 0.f; }
    float l_acc0 = 0.f, l_acc1 = 0.f;

    const size_t kbase = (size_t)(b * L_SEQ) * KV_COLS + kvh * 64;
    const size_t vbase = (size_t)((b * 8 + kvh) * 64) * 2048;

    const int rrk = lane >> 3, cpk = lane & 7;      // K staging: 8 rows x 8 chunks
    const int drv = lane >> 4, cpv = lane & 15;     // V staging: 4 rows x 16 chunks

    // 3-slot ring: slot = 16384 shorts (K 8192 + V 8192)
    unsigned short* bC  = smem;             // tile t
    unsigned short* bN  = smem + 16384;     // tile t+1
    unsigned short* bNN = smem + 32768;     // tile t+2 (being staged)

    // per-wave stage of 1/8 of the K and V tiles (2 x 1KB blocks each)
    auto stage = [&](int T, unsigned short* SL) {
        unsigned short* KS = SL;
        unsigned short* VT = SL + 8192;
        const int k0s = T * 128;
#pragma unroll
        for (int s = 0; s < 2; ++s) {
            const int blk = w * 2 + s;
            gl_lds16(Kb + kbase + (size_t)(k0s + blk * 8 + rrk) * KV_COLS + ((cpk ^ rrk) * 8),
                     KS + blk * 512);
            const int d = blk * 4 + drv;
            gl_lds16(Vtg + vbase + (size_t)d * 2048 + k0s + ((cpv ^ (d & 15)) * 8),
                     VT + blk * 512);
        }
    };

    stage(0, bC);
    stage(1, bN);
    bar_vm4();                    // tile0 landed; tile1 (4 loads) still in flight

    for (int t = 0; t < 16; ++t) {
        if (t <= 13) stage(t + 2, bNN);   // keep 2 tiles in flight

        unsigned short* ksC = bC;
        unsigned short* vtC = bC + 8192;

#pragma unroll
        for (int c = 0; c < 4; ++c) {
            // ---- K A-frags (shared across both q-blocks) ----
            uint4 kf[4];
#pragma unroll
            for (int dh = 0; dh < 4; ++dh)
                kf[dh] = *(const uint4*)&ksC[(c * 32 + l31) * 64 +
                                             (((dh * 2 + h) ^ (l31 & 7)) * 8)];
            // ---- S^T and exp for u=0,1 ----
            unsigned E0[4][2], E1[4][2];
#pragma unroll
            for (int u = 0; u < 2; ++u) {
                f32x16 s;
#pragma unroll
                for (int r = 0; r < 16; ++r) s[r] = 0.f;
                __builtin_amdgcn_s_setprio(1);
#pragma unroll
                for (int dh = 0; dh < 4; ++dh) s = mfma32(kf[dh], qf[u][dh], s);
                __builtin_amdgcn_s_setprio(0);
                float lsum = 0.f;
#pragma unroll
                for (int g = 0; g < 4; ++g) {
                    float e0 = EXP2F(s[4 * g + 0]);
                    float e1 = EXP2F(s[4 * g + 1]);
                    float e2 = EXP2F(s[4 * g + 2]);
                    float e3 = EXP2F(s[4 * g + 3]);
                    lsum += (e0 + e1) + (e2 + e3);
                    if (u == 0) { E0[g][0] = pk_bf16(e0, e1); E0[g][1] = pk_bf16(e2, e3); }
                    else        { E1[g][0] = pk_bf16(e0, e1); E1[g][1] = pk_bf16(e2, e3); }
                }
                if (u == 0) l_acc0 += lsum; else l_acc1 += lsum;
            }
            // ---- PV: V frags shared across both q-blocks ----
#pragma unroll
            for (int tau = 0; tau < 2; ++tau) {
                const int pos = ((c * 4 + tau * 2 + h) ^ (l31 & 15)) * 8;
                uint4 vf0 = *(const uint4*)&vtC[(size_t)l31 * 128 + pos];
                uint4 vf1 = *(const uint4*)&vtC[(size_t)(32 + l31) * 128 + pos];
                // u = 0
                {
                    unsigned x0 = E0[2 * tau][0], z0 = E0[2 * tau + 1][0];
                    unsigned x1 = E0[2 * tau][1], z1 = E0[2 * tau + 1][1];
                    permswap32(x0, z0);
                    permswap32(x1, z1);
                    uint4 pf; pf.x = x0; pf.y = x1; pf.z = z0; pf.w = z1;
                    __builtin_amdgcn_s_setprio(1);
                    o00 = mfma32(vf0, pf, o00);
                    o01 = mfma32(vf1, pf, o01);
                    __builtin_amdgcn_s_setprio(0);
                }
                // u = 1
                {
                    unsigned x0 = E1[2 * tau][0], z0 = E1[2 * tau + 1][0];
                    unsigned x1 = E1[2 * tau][1], z1 = E1[2 * tau + 1][1];
                    permswap32(x0, z0);
                    permswap32(x1, z1);
                    uint4 pf; pf.x = x0; pf.y = x1; pf.z = z0; pf.w = z1;
                    __builtin_amdgcn_s_setprio(1);
                    o10 = mfma32(vf0, pf, o10);
                    o11 = mfma32(vf1, pf, o11);
                    __builtin_amdgcn_s_setprio(0);
                }
            }
        }

        // counted barrier: tile t+1 landed (oldest 4 loads), t+2 stays in flight
        if (t <= 13)      bar_vm4();
        else if (t == 14) bar_vm0();
        else              { __builtin_amdgcn_s_barrier(); asm volatile("" ::: "memory"); }

        unsigned short* tmp = bC; bC = bN; bN = bNN; bNN = tmp;
    }

    // ---- epilogue: per-u normalize + transpose via per-wave LDS + store ----
    __syncthreads();   // nothing outstanding; all waves done with ring
    unsigned* ep = (unsigned*)smem + w * 1088;   // 32 rows x 34 dwords = 4352 B / wave
#pragma unroll
    for (int u = 0; u < 2; ++u) {
        const float la = u ? l_acc1 : l_acc0;
        const float l_tot = la + __shfl_xor(la, 32, 64);
        const float rl = 1.f / l_tot;
#pragma unroll
        for (int dt = 0; dt < 2; ++dt) {
            const f32x16& o = u ? (dt ? o11 : o10) : (dt ? o01 : o00);
#pragma unroll
            for (int g = 0; g < 4; ++g)
#pragma unroll
                for (int pq = 0; pq < 2; ++pq) {
                    const int dv = dt * 16 + 4 * g + 2 * h + pq;
                    ep[l31 * 34 + dv] =
                        pk_bf16(o[4 * g + 2 * pq] * rl, o[4 * g + 2 * pq + 1] * rl);
                }
        }
        __builtin_amdgcn_s_waitcnt(0);   // wave-local LDS write->read ordering
#pragma unroll
        for (int pq = 0; pq < 4; ++pq) {
            const int qr = (lane >> 3) + pq * 8;
            const int cch = lane & 7;
            uint4 vv = *(const uint4*)((const unsigned short*)ep + qr * 68 + cch * 8);
            *(uint4*)(ctx + (size_t)(b * L_SEQ + qbase + u * 32 + qr) * 2048 +
                      hq * 64 + cch * 8) = vv;
        }
        __builtin_amdgcn_s_waitcnt(0);   // reads drained before next-u overwrite
    }
}

// ---------------------------------------------------------------------------

extern "C" void kernel_launch(void* const* d_in, const int* in_sizes, int n_in,
                              void* d_out, int out_size, void* d_ws, size_t ws_size,
                              hipStream_t stream) {
    const float* x  = (const float*)d_in[0];
    const float* Wq = (const float*)d_in[1];
    const float* bq = (const float*)d_in[2];
    const float* Wk = (const float*)d_in[3];
    const float* bk = (const float*)d_in[4];
    const float* Wv = (const float*)d_in[5];
    const float* bv = (const float*)d_in[6];
    const float* Wo = (const float*)d_in[7];
    const float* bo = (const float*)d_in[8];
    float* out = (float*)d_out;

    char* ws = (char*)d_ws;
    size_t off = 0;
    auto alloc = [&](size_t bytes) {
        char* p = ws + off;
        off += (bytes + 255) & ~(size_t)255;
        return p;
    };
    unsigned short* Wqkvt = (unsigned short*)alloc((size_t)3072 * 2048 * 2);
    unsigned short* Wot   = (unsigned short*)alloc((size_t)2048 * 2048 * 2);
    unsigned short* Xb    = (unsigned short*)alloc((size_t)M_ROWS * 2048 * 2);
    unsigned short* Qb    = (unsigned short*)alloc((size_t)M_ROWS * 2048 * 2);
    unsigned short* Kb    = (unsigned short*)alloc((size_t)M_ROWS * KV_COLS * 2);
    unsigned short* Vb    = (unsigned short*)alloc((size_t)M_ROWS * KV_COLS * 2);
    unsigned short* Vt    = (unsigned short*)alloc((size_t)M_ROWS * KV_COLS * 2);
    unsigned short* Cb    = Xb;   // Xb dead after GEMM1; attn writes ctx here

    cast_x_kernel<<<(M_ROWS * 2048 / 4 + 255) / 256, 256, 0, stream>>>(x, Xb,
                                                                       M_ROWS * 2048 / 4);
    transpose_cast_kernel<<<dim3(64, 64), 256, 0, stream>>>(Wq, Wqkvt, 2048, 0);
    transpose_cast_kernel<<<dim3(16, 64), 256, 0, stream>>>(Wk, Wqkvt, 512, 2048);
    transpose_cast_kernel<<<dim3(16, 64), 256, 0, stream>>>(Wv, Wqkvt, 512, 2560);
    transpose_cast_kernel<<<dim3(64, 64), 256, 0, stream>>>(Wo, Wot, 2048, 0);
    gemm_qkv_kernel<<<dim3(32, 24), 256, 0, stream>>>(Xb, Wqkvt, bq, bk, bv, Qb, Kb, Vb);
    transpose_v_kernel<<<dim3(16, 64, 2), 256, 0, stream>>>(Vb, Vt);
    attn_kernel<<<dim3(256), 512, 0, stream>>>(Qb, Kb, Vt, Cb);
    gemm_out_kernel<<<dim3(32, 16), 256, 0, stream>>>(Cb, Wot, bo, out);
}

// Round 5
// 323.933 us; speedup vs baseline: 1.0582x; 1.0582x over previous
//
#include <hip/hip_runtime.h>
#include <cstdint>
#include <cstring>

// ---------------------------------------------------------------------------
// GQA forward, all-bf16 MFMA pipeline.  B=2, L=2048, D=2048, HQ=32, HKV=8, HD=64.
// Round 9: attn reverted to verified Round-7 structure (108 us; Round-8's
// ring+counted-vmcnt graft regressed: VGPR 100->128, MfmaUtil down).
// NEW: bijective XCD swizzle (T1/m204) on BOTH GEMMs -- each XCD owns whole
// B-panel columns (1-1.5 MB, L2-resident) instead of round-robin touching all
// panels from every XCD.  Grids 768/512 are %8==0 so the remap is bijective.
// ---------------------------------------------------------------------------

#define L_SEQ 2048
#define D_MODEL 2048
#define M_ROWS 4096              // B*L
#define KV_COLS 512              // HKV*HD
#define ATTN_SCALE 0.18033688011112042f   // log2(e)/sqrt(64), folded into K

typedef __bf16 bf16x8 __attribute__((ext_vector_type(8)));
typedef float f32x4 __attribute__((ext_vector_type(4)));
typedef float f32x16 __attribute__((ext_vector_type(16)));

__device__ __forceinline__ f32x4 zero4() {
    f32x4 v; v[0] = 0.f; v[1] = 0.f; v[2] = 0.f; v[3] = 0.f; return v;
}

__device__ __forceinline__ unsigned short f2bf(float x) {
    unsigned u = __builtin_bit_cast(unsigned, x);
    u = (u + 0x7FFFu + ((u >> 16) & 1u)) >> 16;   // RNE
    return (unsigned short)u;
}

__device__ __forceinline__ unsigned pk_bf16(float a, float b) {
#if __has_builtin(__builtin_amdgcn_cvt_pk_bf16_f32)
    typedef __bf16 bf16x2 __attribute__((ext_vector_type(2)));
    bf16x2 r = __builtin_amdgcn_cvt_pk_bf16_f32(a, b);
    return __builtin_bit_cast(unsigned, r);
#else
    return (unsigned)f2bf(a) | ((unsigned)f2bf(b) << 16);
#endif
}

__device__ __forceinline__ f32x4 mfma16(uint4 a, uint4 b, f32x4 c) {
    return __builtin_amdgcn_mfma_f32_16x16x32_bf16(
        __builtin_bit_cast(bf16x8, a), __builtin_bit_cast(bf16x8, b), c, 0, 0, 0);
}
__device__ __forceinline__ f32x16 mfma32(uint4 a, uint4 b, f32x16 c) {
    return __builtin_amdgcn_mfma_f32_32x32x16_bf16(
        __builtin_bit_cast(bf16x8, a), __builtin_bit_cast(bf16x8, b), c, 0, 0, 0);
}

__device__ __forceinline__ void gl_lds16(const unsigned short* g, unsigned short* l) {
    __builtin_amdgcn_global_load_lds(
        (const __attribute__((address_space(1))) unsigned int*)g,
        (__attribute__((address_space(3))) unsigned int*)l, 16, 0, 0);
}

#if __has_builtin(__builtin_amdgcn_exp2f)
#define EXP2F(x) __builtin_amdgcn_exp2f(x)
#else
#define EXP2F(x) exp2f(x)
#endif

// a.hi <-> b.lo lane exchange: after this, for lanes<32 a=own, b=partner(+32);
// for lanes>=32 a=partner(-32), b=own.
__device__ __forceinline__ void permswap32(unsigned& a, unsigned& b) {
    asm("v_permlane32_swap_b32 %0, %1" : "+v"(a), "+v"(b));
}

// ---------------------------------------------------------------------------
// prep kernels
// ---------------------------------------------------------------------------

__global__ __launch_bounds__(256) void cast_x_kernel(const float* __restrict__ in,
                                                     unsigned short* __restrict__ out,
                                                     int n4) {
    int i = blockIdx.x * 256 + threadIdx.x;
    if (i >= n4) return;
    float4 v = ((const float4*)in)[i];
    uint2 o;
    o.x = pk_bf16(v.x, v.y);
    o.y = pk_bf16(v.z, v.w);
    ((uint2*)out)[i] = o;
}

__global__ __launch_bounds__(256) void transpose_cast_kernel(const float* __restrict__ in,
                                                             unsigned short* __restrict__ out,
                                                             int N, int row_off) {
    __shared__ float tile[32][33];
    const int n0 = blockIdx.x * 32, k0 = blockIdx.y * 32;
    const int tc = threadIdx.x & 31, tr = threadIdx.x >> 5;
#pragma unroll
    for (int i = 0; i < 4; ++i)
        tile[tr + i * 8][tc] = in[(size_t)(k0 + tr + i * 8) * N + n0 + tc];
    __syncthreads();
#pragma unroll
    for (int i = 0; i < 4; ++i)
        out[(size_t)(row_off + n0 + tr + i * 8) * 2048 + k0 + tc] = f2bf(tile[tc][tr + i * 8]);
}

// Vb [B*L, 512] bf16  ->  Vt [(b*8+kvh)*64+d, 2048] bf16  (per-b transpose)
__global__ __launch_bounds__(256) void transpose_v_kernel(const unsigned short* __restrict__ Vb,
                                                          unsigned short* __restrict__ Vt) {
    __shared__ unsigned short tile[32][33];
    const int c0 = blockIdx.x * 32, l0 = blockIdx.y * 32, b = blockIdx.z;
    const int tc = threadIdx.x & 31, tr = threadIdx.x >> 5;
#pragma unroll
    for (int i = 0; i < 4; ++i)
        tile[tr + i * 8][tc] = Vb[(size_t)(b * 2048 + l0 + tr + i * 8) * KV_COLS + c0 + tc];
    __syncthreads();
#pragma unroll
    for (int i = 0; i < 4; ++i)
        Vt[(size_t)(b * 512 + c0 + tr + i * 8) * 2048 + l0 + tc] = tile[tc][tr + i * 8];
}

// ---------------------------------------------------------------------------
// GEMM core (m97 structure): C[128x128] = A[M,2048] * Bt[N,2048]^T
// ---------------------------------------------------------------------------

__device__ __forceinline__ void gemm_core_2048(const unsigned short* __restrict__ A,
                                               const unsigned short* __restrict__ Bt,
                                               int m_block, int n_block,
                                               unsigned short* smA, unsigned short* smB,
                                               f32x4 acc[4][4]) {
    const int tid = threadIdx.x;
    const int w = tid >> 6, lane = tid & 63;
    const int wm = w >> 1, wn = w & 1;
    const int lr = lane & 15, lg = lane >> 4;

#pragma unroll
    for (int i = 0; i < 4; ++i)
#pragma unroll
        for (int j = 0; j < 4; ++j) acc[i][j] = zero4();

    const int rowA = m_block * 128 + w * 32 + (lane >> 2);
    const int rowB = n_block * 128 + w * 32 + (lane >> 2);
    const int kcol = (lane & 3) * 8;
    const unsigned short* gA0 = A + (size_t)rowA * 2048 + kcol;
    const unsigned short* gA1 = gA0 + (size_t)16 * 2048;
    const unsigned short* gB0 = Bt + (size_t)rowB * 2048 + kcol;
    const unsigned short* gB1 = gB0 + (size_t)16 * 2048;
    unsigned short* lA0 = smA + (w * 32) * 32;
    unsigned short* lA1 = smA + (w * 32 + 16) * 32;
    unsigned short* lB0 = smB + (w * 32) * 32;
    unsigned short* lB1 = smB + (w * 32 + 16) * 32;

    for (int kt = 0; kt < 64; ++kt) {
        gl_lds16(gA0 + kt * 32, lA0);
        gl_lds16(gA1 + kt * 32, lA1);
        gl_lds16(gB0 + kt * 32, lB0);
        gl_lds16(gB1 + kt * 32, lB1);
        __syncthreads();
        uint4 af[4], bfg[4];
#pragma unroll
        for (int i = 0; i < 4; ++i)
            af[i] = *(const uint4*)(smA + (wm * 64 + i * 16 + lr) * 32 + lg * 8);
#pragma unroll
        for (int j = 0; j < 4; ++j)
            bfg[j] = *(const uint4*)(smB + (wn * 64 + j * 16 + lr) * 32 + lg * 8);
#pragma unroll
        for (int i = 0; i < 4; ++i)
#pragma unroll
            for (int j = 0; j < 4; ++j)
                acc[i][j] = mfma16(af[i], bfg[j], acc[i][j]);
        __syncthreads();
    }
}

// GEMM1: X*[Wq|Wk|Wv] + bias -> Q [4096,2048], K [4096,512] (pre-scaled), V [4096,512]
// Grid: 768 linear blocks; bijective XCD swizzle -> each XCD owns 3 full
// B-panel columns (1.5 MB, L2-resident).
__global__ __launch_bounds__(256) void gemm_qkv_kernel(
    const unsigned short* __restrict__ Xb, const unsigned short* __restrict__ Wt,
    const float* __restrict__ bq, const float* __restrict__ bk, const float* __restrict__ bv,
    unsigned short* __restrict__ Qb, unsigned short* __restrict__ Kb,
    unsigned short* __restrict__ Vb) {
    __shared__ __align__(16) unsigned short smA[128 * 32];
    __shared__ __align__(16) unsigned short smB[128 * 32];

    const int p = blockIdx.x;                 // 768 blocks
    const int newid = (p & 7) * 96 + (p >> 3);   // bijective: 768 % 8 == 0
    const int mb = newid & 31, nb = newid >> 5;  // mb in [0,32), nb in [0,24)

    f32x4 acc[4][4];
    gemm_core_2048(Xb, Wt, mb, nb, smA, smB, acc);

    const int tid = threadIdx.x;
    const int w = tid >> 6, lane = tid & 63;
    const int wm = w >> 1, wn = w & 1;
    const int lr = lane & 15, lg = lane >> 4;
    const int nbase = nb * 128;

    unsigned short* outp; int ldo, noff; const float* bias; float scale;
    if (nbase < 2048)      { outp = Qb; ldo = 2048; noff = 0;    bias = bq; scale = 1.f; }
    else if (nbase < 2560) { outp = Kb; ldo = 512;  noff = 2048; bias = bk; scale = ATTN_SCALE; }
    else                   { outp = Vb; ldo = 512;  noff = 2560; bias = bv; scale = 1.f; }

#pragma unroll
    for (int i = 0; i < 4; ++i) {
        const int mrow = mb * 128 + wm * 64 + i * 16 + lg * 4;
#pragma unroll
        for (int j = 0; j < 4; ++j) {
            const int nloc = nbase + wn * 64 + j * 16 + lr - noff;
            const float bb = bias[nloc];
#pragma unroll
            for (int r = 0; r < 4; ++r)
                outp[(size_t)(mrow + r) * ldo + nloc] = f2bf((acc[i][j][r] + bb) * scale);
        }
    }
}

// GEMM2: ctx * Wo^T + bo -> fp32 out [4096,2048]
// Grid: 512 linear blocks; bijective XCD swizzle -> each XCD owns 2 full
// B-panel columns (1 MB, L2-resident).
__global__ __launch_bounds__(256) void gemm_out_kernel(
    const unsigned short* __restrict__ Cb, const unsigned short* __restrict__ Wot,
    const float* __restrict__ bo, float* __restrict__ out) {
    __shared__ __align__(16) unsigned short smA[128 * 32];
    __shared__ __align__(16) unsigned short smB[128 * 32];

    const int p = blockIdx.x;                 // 512 blocks
    const int newid = (p & 7) * 64 + (p >> 3);   // bijective: 512 % 8 == 0
    const int mb = newid & 31, nb = newid >> 5;  // mb in [0,32), nb in [0,16)

    f32x4 acc[4][4];
    gemm_core_2048(Cb, Wot, mb, nb, smA, smB, acc);

    const int tid = threadIdx.x;
    const int w = tid >> 6, lane = tid & 63;
    const int wm = w >> 1, wn = w & 1;
    const int lr = lane & 15, lg = lane >> 4;

#pragma unroll
    for (int i = 0; i < 4; ++i) {
        const int mrow = mb * 128 + wm * 64 + i * 16 + lg * 4;
#pragma unroll
        for (int j = 0; j < 4; ++j) {
            const int ncol = nb * 128 + wn * 64 + j * 16 + lr;
            const float bb = bo[ncol];
#pragma unroll
            for (int r = 0; r < 4; ++r)
                out[(size_t)(mrow + r) * 2048 + ncol] = acc[i][j][r] + bb;
        }
    }
}

// ---------------------------------------------------------------------------
// Attention (Round-7 verified, 108 us): block = 512 thr = 8 waves; each wave
// owns 64 q (2 q-frags, u=0/1) of one q-head; block covers 512 q.  Grid
// 4 x 32 x 2 = 256 blocks (1/CU).  K tile [128 k][64 d] and V^T tile
// [64 d][128 k] double-buffered (64 KB LDS); next tile staged via
// global_load_lds BEFORE current tile's compute; one __syncthreads per iter.
// P-fragment assembly via v_permlane32_swap_b32; s_setprio(1) around MFMA
// clusters.  Source-side XOR chunk swizzle.  No online max.
// ---------------------------------------------------------------------------

__global__ __launch_bounds__(512, 2) void attn_kernel(const unsigned short* __restrict__ Qb,
                                                      const unsigned short* __restrict__ Kb,
                                                      const unsigned short* __restrict__ Vtg,
                                                      unsigned short* __restrict__ ctx) {
    __shared__ __align__(16) unsigned short smem[32768];   // 64 KB: 2 x (K 16KB + V 16KB)

    const int qt = blockIdx.x, hq = blockIdx.y, b = blockIdx.z;
    const int kvh = hq >> 2;
    const int tid = threadIdx.x;
    const int w = tid >> 6, lane = tid & 63;
    const int l31 = lane & 31, h = lane >> 5;

    // Q B-frags for two 32-q blocks (u=0,1): B[n=q=l31][k=d], k-elem = h*8+j
    const int qbase = qt * 512 + w * 64;
    uint4 qf[2][4];
#pragma unroll
    for (int u = 0; u < 2; ++u) {
        const unsigned short* qp =
            Qb + (size_t)(b * L_SEQ + qbase + u * 32 + l31) * 2048 + hq * 64;
#pragma unroll
        for (int dh = 0; dh < 4; ++dh)
            qf[u][dh] = *(const uint4*)(qp + dh * 16 + h * 8);
    }

    f32x16 o00, o01, o10, o11;   // o[u][d-half]
#pragma unroll
    for (int r = 0; r < 16; ++r) { o00[r] = 0.f; o01[r] = 0.f; o10[r] = 0.f; o11[r] = 0.f; }
    float l_acc0 = 0.f, l_acc1 = 0.f;

    const size_t kbase = (size_t)(b * L_SEQ) * KV_COLS + kvh * 64;
    const size_t vbase = (size_t)((b * 8 + kvh) * 64) * 2048;

    const int rrk = lane >> 3, cpk = lane & 7;      // K staging: 8 rows x 8 chunks
    const int drv = lane >> 4, cpv = lane & 15;     // V staging: 4 rows x 16 chunks

    unsigned short* ksC = smem;                     // current K [128][64]
    unsigned short* vtC = smem + 8192;              // current V^T [64][128]
    unsigned short* ksN = smem + 16384;             // next K
    unsigned short* vtN = smem + 24576;             // next V^T

    // per-wave stage of 1/8 of the K and V tiles (2 x 1KB blocks each)
    auto stage = [&](int T, unsigned short* KS, unsigned short* VT) {
        const int k0s = T * 128;
#pragma unroll
        for (int s = 0; s < 2; ++s) {
            const int blk = w * 2 + s;
            gl_lds16(Kb + kbase + (size_t)(k0s + blk * 8 + rrk) * KV_COLS + ((cpk ^ rrk) * 8),
                     KS + blk * 512);
            const int d = blk * 4 + drv;
            gl_lds16(Vtg + vbase + (size_t)d * 2048 + k0s + ((cpv ^ (d & 15)) * 8),
                     VT + blk * 512);
        }
    };

    stage(0, ksC, vtC);
    __syncthreads();                 // prologue: only fully-exposed load latency

    for (int t = 0; t < 16; ++t) {
        if (t < 15) stage(t + 1, ksN, vtN);   // prefetch next tile (in flight all iter)

#pragma unroll
        for (int c = 0; c < 4; ++c) {
            // ---- K A-frags (shared across both q-blocks) ----
            uint4 kf[4];
#pragma unroll
            for (int dh = 0; dh < 4; ++dh)
                kf[dh] = *(const uint4*)&ksC[(c * 32 + l31) * 64 +
                                             (((dh * 2 + h) ^ (l31 & 7)) * 8)];
            // ---- S^T and exp for u=0,1 ----
            unsigned E0[4][2], E1[4][2];
#pragma unroll
            for (int u = 0; u < 2; ++u) {
                f32x16 s;
#pragma unroll
                for (int r = 0; r < 16; ++r) s[r] = 0.f;
                __builtin_amdgcn_s_setprio(1);
#pragma unroll
                for (int dh = 0; dh < 4; ++dh) s = mfma32(kf[dh], qf[u][dh], s);
                __builtin_amdgcn_s_setprio(0);
                float lsum = 0.f;
#pragma unroll
                for (int g = 0; g < 4; ++g) {
                    float e0 = EXP2F(s[4 * g + 0]);
                    float e1 = EXP2F(s[4 * g + 1]);
                    float e2 = EXP2F(s[4 * g + 2]);
                    float e3 = EXP2F(s[4 * g + 3]);
                    lsum += (e0 + e1) + (e2 + e3);
                    if (u == 0) { E0[g][0] = pk_bf16(e0, e1); E0[g][1] = pk_bf16(e2, e3); }
                    else        { E1[g][0] = pk_bf16(e0, e1); E1[g][1] = pk_bf16(e2, e3); }
                }
                if (u == 0) l_acc0 += lsum; else l_acc1 += lsum;
            }
            // ---- PV: V frags shared across both q-blocks ----
#pragma unroll
            for (int tau = 0; tau < 2; ++tau) {
                const int pos = ((c * 4 + tau * 2 + h) ^ (l31 & 15)) * 8;
                uint4 vf0 = *(const uint4*)&vtC[(size_t)l31 * 128 + pos];
                uint4 vf1 = *(const uint4*)&vtC[(size_t)(32 + l31) * 128 + pos];
                // u = 0
                {
                    unsigned x0 = E0[2 * tau][0], z0 = E0[2 * tau + 1][0];
                    unsigned x1 = E0[2 * tau][1], z1 = E0[2 * tau + 1][1];
                    permswap32(x0, z0);
                    permswap32(x1, z1);
                    uint4 pf; pf.x = x0; pf.y = x1; pf.z = z0; pf.w = z1;
                    __builtin_amdgcn_s_setprio(1);
                    o00 = mfma32(vf0, pf, o00);
                    o01 = mfma32(vf1, pf, o01);
                    __builtin_amdgcn_s_setprio(0);
                }
                // u = 1
                {
                    unsigned x0 = E1[2 * tau][0], z0 = E1[2 * tau + 1][0];
                    unsigned x1 = E1[2 * tau][1], z1 = E1[2 * tau + 1][1];
                    permswap32(x0, z0);
                    permswap32(x1, z1);
                    uint4 pf; pf.x = x0; pf.y = x1; pf.z = z0; pf.w = z1;
                    __builtin_amdgcn_s_setprio(1);
                    o10 = mfma32(vf0, pf, o10);
                    o11 = mfma32(vf1, pf, o11);
                    __builtin_amdgcn_s_setprio(0);
                }
            }
        }

        __syncthreads();   // drains vmcnt(0): next tile landed; all reads of cur done
        unsigned short* tk = ksC; ksC = ksN; ksN = tk;
        unsigned short* tv = vtC; vtC = vtN; vtN = tv;
    }

    // ---- epilogue: per-u normalize + transpose via per-wave LDS + store ----
    // (last loop iteration ended with __syncthreads -> smem free to reuse)
    unsigned* ep = (unsigned*)smem + w * 1088;   // 32 rows x 34 dwords = 4352 B / wave
#pragma unroll
    for (int u = 0; u < 2; ++u) {
        const float la = u ? l_acc1 : l_acc0;
        const float l_tot = la + __shfl_xor(la, 32, 64);
        const float rl = 1.f / l_tot;
#pragma unroll
        for (int dt = 0; dt < 2; ++dt) {
            const f32x16& o = u ? (dt ? o11 : o10) : (dt ? o01 : o00);
#pragma unroll
            for (int g = 0; g < 4; ++g)
#pragma unroll
                for (int p = 0; p < 2; ++p) {
                    const int dv = dt * 16 + 4 * g + 2 * h + p;
                    ep[l31 * 34 + dv] =
                        pk_bf16(o[4 * g + 2 * p] * rl, o[4 * g + 2 * p + 1] * rl);
                }
        }
        __builtin_amdgcn_s_waitcnt(0);   // wave-local LDS write->read ordering
#pragma unroll
        for (int p = 0; p < 4; ++p) {
            const int qr = (lane >> 3) + p * 8;
            const int cch = lane & 7;
            uint4 vv = *(const uint4*)((const unsigned short*)ep + qr * 68 + cch * 8);
            *(uint4*)(ctx + (size_t)(b * L_SEQ + qbase + u * 32 + qr) * 2048 +
                      hq * 64 + cch * 8) = vv;
        }
        __builtin_amdgcn_s_waitcnt(0);   // reads drained before next-u overwrite
    }
}

// ---------------------------------------------------------------------------

extern "C" void kernel_launch(void* const* d_in, const int* in_sizes, int n_in,
                              void* d_out, int out_size, void* d_ws, size_t ws_size,
                              hipStream_t stream) {
    const float* x  = (const float*)d_in[0];
    const float* Wq = (const float*)d_in[1];
    const float* bq = (const float*)d_in[2];
    const float* Wk = (const float*)d_in[3];
    const float* bk = (const float*)d_in[4];
    const float* Wv = (const float*)d_in[5];
    const float* bv = (const float*)d_in[6];
    const float* Wo = (const float*)d_in[7];
    const float* bo = (const float*)d_in[8];
    float* out = (float*)d_out;

    char* ws = (char*)d_ws;
    size_t off = 0;
    auto alloc = [&](size_t bytes) {
        char* p = ws + off;
        off += (bytes + 255) & ~(size_t)255;
        return p;
    };
    unsigned short* Wqkvt = (unsigned short*)alloc((size_t)3072 * 2048 * 2);
    unsigned short* Wot   = (unsigned short*)alloc((size_t)2048 * 2048 * 2);
    unsigned short* Xb    = (unsigned short*)alloc((size_t)M_ROWS * 2048 * 2);
    unsigned short* Qb    = (unsigned short*)alloc((size_t)M_ROWS * 2048 * 2);
    unsigned short* Kb    = (unsigned short*)alloc((size_t)M_ROWS * KV_COLS * 2);
    unsigned short* Vb    = (unsigned short*)alloc((size_t)M_ROWS * KV_COLS * 2);
    unsigned short* Vt    = (unsigned short*)alloc((size_t)M_ROWS * KV_COLS * 2);
    unsigned short* Cb    = Xb;   // Xb dead after GEMM1; attn writes ctx here

    cast_x_kernel<<<(M_ROWS * 2048 / 4 + 255) / 256, 256, 0, stream>>>(x, Xb,
                                                                       M_ROWS * 2048 / 4);
    transpose_cast_kernel<<<dim3(64, 64), 256, 0, stream>>>(Wq, Wqkvt, 2048, 0);
    transpose_cast_kernel<<<dim3(16, 64), 256, 0, stream>>>(Wk, Wqkvt, 512, 2048);
    transpose_cast_kernel<<<dim3(16, 64), 256, 0, stream>>>(Wv, Wqkvt, 512, 2560);
    transpose_cast_kernel<<<dim3(64, 64), 256, 0, stream>>>(Wo, Wot, 2048, 0);
    gemm_qkv_kernel<<<dim3(768), 256, 0, stream>>>(Xb, Wqkvt, bq, bk, bv, Qb, Kb, Vb);
    transpose_v_kernel<<<dim3(16, 64, 2), 256, 0, stream>>>(Vb, Vt);
    attn_kernel<<<dim3(4, 32, 2), 512, 0, stream>>>(Qb, Kb, Vt, Cb);
    gemm_out_kernel<<<dim3(512), 256, 0, stream>>>(Cb, Wot, bo, out);
}